// Round 1
// baseline (792.300 us; speedup 1.0000x reference)
//
#include <hip/hip_runtime.h>

// DynamicSparseScaledDotProductAttention on MI355X (gfx950)
// q,k,v: [32, 2048, 64] fp32; gate_w: [1,64]; gate_b: [1]
// outputs (tuple): out [32,2048,64] fp32, attn [32,2048,2048] fp32
//
// Restructured v2:
//  - Gate-split: sigmoid(q.w)>0.5 <=> q.w>0. Gated-off rows attend ONLY to the
//    5-key window |i-j|<=2 -> exact fp32 path (no MFMA), attn row = zeros + 5 vals.
//    Gated-on rows have NO mask at all (window ⊂ full) -> clean flash, no per-elem
//    mask logic.
//  - Prep kernel pre-converts K -> bf16 [bh][key][d] and V -> bf16 TRANSPOSED
//    [bh][d][key] in workspace: main kernel loads MFMA fragments directly
//    global->VGPR (dwordx4), zero staging LDS, zero f2bf in the hot loop.
//  - Per-wave-owned 16-row tiles, denominators reduced in-wave: the key loops have
//    NO __syncthreads (only one barrier after the gate sort). Per-wave private
//    Pbuf does the P C-layout -> A-layout transpose (in-order LDS within a wave).
//
// MFMA mfma_f32_16x16x32_bf16 layouts (HW-verified per guide):
//   A-frag: lane holds A[m=lane&15][k=(lane>>4)*8 + j], j=0..7
//   B-frag: lane holds B[k=(lane>>4)*8+j][n=lane&15]
//   C/D   : lane holds D[row=(lane>>4)*4 + r][col=lane&15], r=0..3

typedef short bf16x8 __attribute__((ext_vector_type(8)));
typedef float f32x4  __attribute__((ext_vector_type(4)));

#define LSEQ 2048
#define DDIM 64
#define PB_STRIDE 36   // Pbuf row stride (f32); 144B rows, 16B-aligned reads

__device__ __forceinline__ unsigned short f2bf(float x) {
    // round-to-nearest-even fp32 -> bf16
    unsigned int u = __float_as_uint(x);
    u += 0x7FFFu + ((u >> 16) & 1u);
    return (unsigned short)(u >> 16);
}

__device__ __forceinline__ unsigned int pk2f(float a, float b) {
    return (unsigned int)f2bf(a) | ((unsigned int)f2bf(b) << 16);
}

__device__ __forceinline__ unsigned int pk2u(unsigned short a, unsigned short b) {
    return (unsigned int)a | ((unsigned int)b << 16);
}

__device__ __forceinline__ float pick5(int jj, float e0, float e1, float e2,
                                       float e3, float e4) {
    float r = 0.f;
    r = (jj == 0) ? e0 : r;
    r = (jj == 1) ? e1 : r;
    r = (jj == 2) ? e2 : r;
    r = (jj == 3) ? e3 : r;
    r = (jj == 4) ? e4 : r;
    return r;
}

// ---------------- prep: K -> bf16 [bh][key][d]; V -> bf16 transposed [bh][d][key]
__global__ __launch_bounds__(256)
void dsa_prep(const float* __restrict__ K, const float* __restrict__ V,
              unsigned short* __restrict__ Kb, unsigned short* __restrict__ Vt)
{
    const int bh  = blockIdx.x >> 5;
    const int k0  = (blockIdx.x & 31) << 6;   // 64-key chunk
    const int tid = threadIdx.x;
    __shared__ unsigned short tileT[64][73];  // [d][key] (+pad)

    const int key = tid >> 2;                 // 0..63
    const int d0  = (tid & 3) << 4;           // 0,16,32,48
    const float* srcK = K + ((size_t)bh * LSEQ + k0 + key) * DDIM + d0;
    const float* srcV = V + ((size_t)bh * LSEQ + k0 + key) * DDIM + d0;
    {   // K: straight convert, 16 elems/thread, 2x16B stores
        uint4 w0, w1;
        w0.x = pk2f(srcK[0],  srcK[1]);  w0.y = pk2f(srcK[2],  srcK[3]);
        w0.z = pk2f(srcK[4],  srcK[5]);  w0.w = pk2f(srcK[6],  srcK[7]);
        w1.x = pk2f(srcK[8],  srcK[9]);  w1.y = pk2f(srcK[10], srcK[11]);
        w1.z = pk2f(srcK[12], srcK[13]); w1.w = pk2f(srcK[14], srcK[15]);
        unsigned short* dst = Kb + ((size_t)bh * LSEQ + k0 + key) * DDIM + d0;
        *(uint4*)(dst)     = w0;
        *(uint4*)(dst + 8) = w1;
    }
    #pragma unroll
    for (int j = 0; j < 16; ++j) tileT[d0 + j][key] = f2bf(srcV[j]);
    __syncthreads();
    {   // V: write transposed rows coalesced
        const int d   = tid >> 2;
        const int kk0 = (tid & 3) << 4;
        uint4 w0, w1;
        w0.x = pk2u(tileT[d][kk0 + 0],  tileT[d][kk0 + 1]);
        w0.y = pk2u(tileT[d][kk0 + 2],  tileT[d][kk0 + 3]);
        w0.z = pk2u(tileT[d][kk0 + 4],  tileT[d][kk0 + 5]);
        w0.w = pk2u(tileT[d][kk0 + 6],  tileT[d][kk0 + 7]);
        w1.x = pk2u(tileT[d][kk0 + 8],  tileT[d][kk0 + 9]);
        w1.y = pk2u(tileT[d][kk0 + 10], tileT[d][kk0 + 11]);
        w1.z = pk2u(tileT[d][kk0 + 12], tileT[d][kk0 + 13]);
        w1.w = pk2u(tileT[d][kk0 + 14], tileT[d][kk0 + 15]);
        unsigned short* dst = Vt + (size_t)bh * DDIM * LSEQ + (size_t)d * LSEQ + k0 + kk0;
        *(uint4*)(dst)     = w0;
        *(uint4*)(dst + 8) = w1;
    }
}

// ---------------- main
__global__ __launch_bounds__(256, 4)
void dsa_main(const float* __restrict__ Q,
              const unsigned short* __restrict__ Kb,   // bf16 [bh][key][d]
              const unsigned short* __restrict__ Vt,   // bf16 [bh][d][key]
              const float* __restrict__ K32,
              const float* __restrict__ V32,
              const float* __restrict__ GW,
              const float* __restrict__ GB,
              float* __restrict__ OUT,
              float* __restrict__ ATT)
{
    __shared__ float Pbuf[4][16 * PB_STRIDE];  // per-wave private P transpose tile
    __shared__ int   sidx[64];                 // full rows first, then window rows
    __shared__ int   gShared;

    const int bx   = blockIdx.x;
    const int bh   = bx >> 5;
    const int q0   = (bx & 31) << 6;
    const int tid  = threadIdx.x;
    const int wave = tid >> 6;
    const int lane = tid & 63;
    const int m16  = lane & 15;
    const int quad = lane >> 4;

    const float* qb = Q + ((size_t)bh * LSEQ + q0) * DDIM;

    // ---- gate (exact fp32: sigmoid(x)>0.5 <=> x>0) + ballot sort, wave 0 only ----
    if (wave == 0) {
        const float* qr = qb + lane * DDIM;
        float a = 0.f;
        #pragma unroll 8
        for (int d = 0; d < DDIM; ++d) a += qr[d] * GW[d];
        a += GB[0];
        const bool gt = (a > 0.f);
        const unsigned long long b = __ballot(gt);
        const int below = __popcll(b & ((1ull << lane) - 1ull));
        const int g     = __popcll(b);
        const int pos   = gt ? below : (g + (lane - below));
        sidx[pos] = lane;
        if (lane == 0) gShared = g;
    }
    __syncthreads();
    const int g = gShared;
    const int T = (g + 15) >> 4;   // full 16-row tiles (0..4)

    // =================== full-attention flash (wave owns one tile) ===================
    if (wave < T) {
        const unsigned short* kbb = Kb + (size_t)bh * LSEQ * DDIM;
        const unsigned short* vtb = Vt + (size_t)bh * DDIM * LSEQ;
        const int  myIdx = (wave << 4) + m16;
        const bool valid = myIdx < g;
        const int  srow  = sidx[valid ? myIdx : (g - 1)];

        // persistent Q A-frags for this lane's query row
        bf16x8 qfrag[2];
        {
            const float* qr = qb + srow * DDIM + (quad << 3);
            #pragma unroll
            for (int db = 0; db < 2; ++db) {
                const float* p = qr + db * 32;
                bf16x8 f;
                #pragma unroll
                for (int j = 0; j < 8; ++j) f[j] = (short)f2bf(p[j]);
                qfrag[db] = f;
            }
        }

        const unsigned short* kp0 = kbb + (size_t)m16 * DDIM + (quad << 3);

        // ---- pass 1: denominators (no masking!) with K prefetch, no barriers ----
        float lsum[4] = {0.f, 0.f, 0.f, 0.f};
        bf16x8 c0 = *(const bf16x8*)(kp0);
        bf16x8 c1 = *(const bf16x8*)(kp0 + 32);
        bf16x8 c2 = *(const bf16x8*)(kp0 + 16 * DDIM);
        bf16x8 c3 = *(const bf16x8*)(kp0 + 16 * DDIM + 32);
        for (int kt = 0; kt < 64; ++kt) {
            const unsigned short* np = kp0 + (size_t)(((kt + 1) & 63) * 32) * DDIM;
            bf16x8 n0 = *(const bf16x8*)(np);
            bf16x8 n1 = *(const bf16x8*)(np + 32);
            bf16x8 n2 = *(const bf16x8*)(np + 16 * DDIM);
            bf16x8 n3 = *(const bf16x8*)(np + 16 * DDIM + 32);
            f32x4 a0 = {0.f, 0.f, 0.f, 0.f}, a1 = {0.f, 0.f, 0.f, 0.f};
            a0 = __builtin_amdgcn_mfma_f32_16x16x32_bf16(qfrag[0], c0, a0, 0, 0, 0);
            a0 = __builtin_amdgcn_mfma_f32_16x16x32_bf16(qfrag[1], c1, a0, 0, 0, 0);
            a1 = __builtin_amdgcn_mfma_f32_16x16x32_bf16(qfrag[0], c2, a1, 0, 0, 0);
            a1 = __builtin_amdgcn_mfma_f32_16x16x32_bf16(qfrag[1], c3, a1, 0, 0, 0);
            #pragma unroll
            for (int r = 0; r < 4; ++r)
                lsum[r] += __expf(a0[r] * 0.125f) + __expf(a1[r] * 0.125f);
            c0 = n0; c1 = n1; c2 = n2; c3 = n3;
        }
        float inv[4];
        #pragma unroll
        for (int r = 0; r < 4; ++r) {
            float x = lsum[r];
            x += __shfl_xor(x, 1); x += __shfl_xor(x, 2);
            x += __shfl_xor(x, 4); x += __shfl_xor(x, 8);
            inv[r] = 1.0f / x;
        }

        // ---- pass 2: recompute, write attn, accumulate P.V — no barriers ----
        f32x4 oacc[4];
        #pragma unroll
        for (int dt = 0; dt < 4; ++dt) oacc[dt] = (f32x4){0.f, 0.f, 0.f, 0.f};
        float* pw  = &Pbuf[wave][0];
        float* ap0 = ATT + ((size_t)(bh * LSEQ + q0 + srow)) * LSEQ + (quad << 3);
        const unsigned short* vp0 = vtb + (size_t)m16 * LSEQ + (quad << 3);

        for (int kt = 0; kt < 64; ++kt) {
            const unsigned short* kp = kp0 + (size_t)(kt * 32) * DDIM;
            bf16x8 k0 = *(const bf16x8*)(kp);
            bf16x8 k1 = *(const bf16x8*)(kp + 32);
            bf16x8 k2 = *(const bf16x8*)(kp + 16 * DDIM);
            bf16x8 k3 = *(const bf16x8*)(kp + 16 * DDIM + 32);
            const unsigned short* vp = vp0 + kt * 32;   // issue V loads early
            bf16x8 v0 = *(const bf16x8*)(vp);
            bf16x8 v1 = *(const bf16x8*)(vp + 16 * LSEQ);
            bf16x8 v2 = *(const bf16x8*)(vp + 32 * LSEQ);
            bf16x8 v3 = *(const bf16x8*)(vp + 48 * LSEQ);

            f32x4 a0 = {0.f, 0.f, 0.f, 0.f}, a1 = {0.f, 0.f, 0.f, 0.f};
            a0 = __builtin_amdgcn_mfma_f32_16x16x32_bf16(qfrag[0], k0, a0, 0, 0, 0);
            a0 = __builtin_amdgcn_mfma_f32_16x16x32_bf16(qfrag[1], k1, a0, 0, 0, 0);
            a1 = __builtin_amdgcn_mfma_f32_16x16x32_bf16(qfrag[0], k2, a1, 0, 0, 0);
            a1 = __builtin_amdgcn_mfma_f32_16x16x32_bf16(qfrag[1], k3, a1, 0, 0, 0);

            // normalized P -> per-wave Pbuf (C-layout rows; in-order LDS, no barrier)
            #pragma unroll
            for (int r = 0; r < 4; ++r) {
                const int prow = (quad << 2) + r;
                pw[prow * PB_STRIDE + m16]      = __expf(a0[r] * 0.125f) * inv[r];
                pw[prow * PB_STRIDE + 16 + m16] = __expf(a1[r] * 0.125f) * inv[r];
            }
            // A-layout read-back; doubles as coalesced attn store
            const float* prd = pw + m16 * PB_STRIDE + (quad << 3);
            f32x4 p0 = *(const f32x4*)(prd);
            f32x4 p1 = *(const f32x4*)(prd + 4);
            if (valid) {
                float* ap = ap0 + kt * 32;
                *(f32x4*)(ap)     = p0;
                *(f32x4*)(ap + 4) = p1;
            }
            bf16x8 pf;
            #pragma unroll
            for (int j = 0; j < 4; ++j) {
                pf[j]     = (short)f2bf(p0[j]);
                pf[4 + j] = (short)f2bf(p1[j]);
            }
            oacc[0] = __builtin_amdgcn_mfma_f32_16x16x32_bf16(pf, v0, oacc[0], 0, 0, 0);
            oacc[1] = __builtin_amdgcn_mfma_f32_16x16x32_bf16(pf, v1, oacc[1], 0, 0, 0);
            oacc[2] = __builtin_amdgcn_mfma_f32_16x16x32_bf16(pf, v2, oacc[2], 0, 0, 0);
            oacc[3] = __builtin_amdgcn_mfma_f32_16x16x32_bf16(pf, v3, oacc[3], 0, 0, 0);
        }
        // epilogue (C-layout rows; P was normalized, no rescale)
        #pragma unroll
        for (int r = 0; r < 4; ++r) {
            const int idx = (wave << 4) + (quad << 2) + r;
            if (idx < g) {
                const int orow = sidx[idx];
                float* ob = OUT + ((size_t)(bh * LSEQ + q0 + orow)) * DDIM + m16;
                ob[0]  = oacc[0][r];
                ob[16] = oacc[1][r];
                ob[32] = oacc[2][r];
                ob[48] = oacc[3][r];
            }
        }
    }

    // =================== window rows (gate off): exact fp32, 5-key softmax ===========
    const int nw    = 64 - g;
    const int nww   = (T < 4) ? (4 - T) : 4;
    const int wslot = (T < 4) ? (wave - T) : wave;
    if (wslot >= 0 && nw > 0) {
        for (int ii = wslot; ii < nw; ii += nww) {
            const int row = sidx[g + ii];
            const int i   = q0 + row;                       // global query index
            const float qd = qb[row * DDIM + lane];         // d = lane

            float e[5];
            float denom = 0.f;
            #pragma unroll
            for (int jj = 0; jj < 5; ++jj) {
                const int  j  = i - 2 + jj;
                const bool ok = (j >= 0) && (j < LSEQ);
                const int  jc = ok ? j : 0;
                float t = qd * K32[((size_t)bh * LSEQ + jc) * DDIM + lane];
                t += __shfl_xor(t, 1);  t += __shfl_xor(t, 2);
                t += __shfl_xor(t, 4);  t += __shfl_xor(t, 8);
                t += __shfl_xor(t, 16); t += __shfl_xor(t, 32);
                const float ee = ok ? __expf(t * 0.125f) : 0.f;
                e[jj] = ee;
                denom += ee;
            }
            const float invd = 1.f / denom;
            #pragma unroll
            for (int jj = 0; jj < 5; ++jj) e[jj] *= invd;

            // out row: o[d] = sum_j p_j * V[j][d]  (lane = d, coalesced)
            float o = 0.f;
            #pragma unroll
            for (int jj = 0; jj < 5; ++jj) {
                const int  j  = i - 2 + jj;
                const int  jc = (j >= 0 && j < LSEQ) ? j : 0;
                o += e[jj] * V32[((size_t)bh * LSEQ + jc) * DDIM + lane];
            }
            OUT[((size_t)(bh * LSEQ + i)) * DDIM + lane] = o;

            // attn row: zeros with the <=5 window values merged in-register
            float* ar = ATT + ((size_t)(bh * LSEQ + i)) * LSEQ;
            const int jlo = i - 2;
            #pragma unroll
            for (int it = 0; it < 8; ++it) {
                const int c = (it << 8) + (lane << 2);
                f32x4 z = {0.f, 0.f, 0.f, 0.f};
                if (c + 3 >= jlo && c <= jlo + 4) {
                    #pragma unroll
                    for (int t4 = 0; t4 < 4; ++t4)
                        z[t4] = pick5(c + t4 - jlo, e[0], e[1], e[2], e[3], e[4]);
                }
                *(f32x4*)(ar + c) = z;
            }
        }
    }
}

extern "C" void kernel_launch(void* const* d_in, const int* in_sizes, int n_in,
                              void* d_out, int out_size, void* d_ws, size_t ws_size,
                              hipStream_t stream) {
    const float* q  = (const float*)d_in[0];
    const float* k  = (const float*)d_in[1];
    const float* v  = (const float*)d_in[2];
    const float* gw = (const float*)d_in[3];
    const float* gb = (const float*)d_in[4];

    float* out  = (float*)d_out;                      // [32,2048,64]
    float* attn = out + (size_t)32 * 2048 * 64;       // [32,2048,2048]

    // workspace: Kb bf16 [32][2048][64] (8MB) + Vt bf16 [32][64][2048] (8MB)
    unsigned short* Kb = (unsigned short*)d_ws;
    unsigned short* Vt = Kb + (size_t)32 * 2048 * 64;

    dim3 block(256);
    dsa_prep<<<dim3(32 * 32), block, 0, stream>>>(k, v, Kb, Vt);
    dsa_main<<<dim3(32 * 32), block, 0, stream>>>(q, Kb, Vt, k, v, gw, gb, out, attn);
}